// Round 13
// baseline (26.426 us; speedup 1.0000x reference)
//
#include <hip/hip_runtime.h>
#include <hip/hip_fp16.h>
#include <math.h>

typedef unsigned short u16;
typedef unsigned int   u32;
typedef u16 us2 __attribute__((ext_vector_type(2)));

constexpr int BB = 2, CC = 4, DD = 64, HH = 64, WW = 64;
constexpr int HW   = HH * WW;      // 4096
constexpr int DHW  = DD * HW;      // 262144
constexpr int CDHW = CC * DHW;     // 1048576
constexpr int NTOT = BB * CDHW;    // 2097152
constexpr int NBLK = 512;
constexpr u32 SENT = 50000;        // u16 "infinity": 50000+2*3969 < 65536 (SWAR-safe)

__device__ __forceinline__ u32 pkmin(u32 a, u32 b) {
    us2 r = __builtin_elementwise_min(__builtin_bit_cast(us2, a),
                                      __builtin_bit_cast(us2, b));
    return __builtin_bit_cast(u32, r);
}
__device__ __forceinline__ u32 pkmax(u32 a, u32 b) {
    us2 r = __builtin_elementwise_max(__builtin_bit_cast(us2, a),
                                      __builtin_bit_cast(us2, b));
    return __builtin_bit_cast(u32, r);
}
__device__ __forceinline__ float2 h2f(u32 w) {
    return __half22float2(__builtin_bit_cast(__half2, w));
}

// Min-plus over rows of a [64][64] u16 LDS slab with outward early-exit
// (R12-proven, lossless: only provably-non-improving j rows are skipped).
#define MINPLUS_SCAN(SRC)                                                      \
    u32 a0 = 0xFFFFFFFFu, a1 = 0xFFFFFFFFu, a2 = 0xFFFFFFFFu, a3 = 0xFFFFFFFFu;\
    {                                                                          \
        const int I = (t >> 6) * 8;                                            \
        _Pragma("unroll")                                                      \
        for (int k = 0; k < 8; ++k) {                                          \
            const int jj = I + k;                                              \
            const uint4 v = *reinterpret_cast<const uint4*>(&SRC[jj * 64 + wg]);\
            const int  df = i - jj;                                            \
            const u32  cst = (u32)(df * df) * 0x00010001u;                     \
            a0 = pkmin(a0, v.x + cst); a1 = pkmin(a1, v.y + cst);              \
            a2 = pkmin(a2, v.z + cst); a3 = pkmin(a3, v.w + cst);              \
        }                                                                      \
        int jlo = I - 1, jhi = I + 8;                                          \
        while (jlo >= 0 || jhi < 64) {                                         \
            const u32 pk  = pkmax(pkmax(a0, a1), pkmax(a2, a3));               \
            const u32 lo16 = pk & 0xFFFFu, hi16 = pk >> 16;                    \
            const u32 mm  = lo16 > hi16 ? lo16 : hi16;                         \
            const int dlo = (jlo >= 0) ? (i - jlo) : 1000;                     \
            const int dhi = (jhi < 64) ? (jhi - i) : 1000;                     \
            const int dm  = dlo < dhi ? dlo : dhi;                             \
            if (__all((u32)(dm * dm) >= mm)) break;                            \
            if (jlo >= 0) {                                                    \
                const uint4 v = *reinterpret_cast<const uint4*>(&SRC[jlo * 64 + wg]);\
                const int  df = i - jlo;                                       \
                const u32  cst = (u32)(df * df) * 0x00010001u;                 \
                a0 = pkmin(a0, v.x + cst); a1 = pkmin(a1, v.y + cst);          \
                a2 = pkmin(a2, v.z + cst); a3 = pkmin(a3, v.w + cst);          \
                --jlo;                                                         \
            }                                                                  \
            if (jhi < 64) {                                                    \
                const uint4 v = *reinterpret_cast<const uint4*>(&SRC[jhi * 64 + wg]);\
                const int  df = jhi - i;                                       \
                const u32  cst = (u32)(df * df) * 0x00010001u;                 \
                a0 = pkmin(a0, v.x + cst); a1 = pkmin(a1, v.y + cst);          \
                a2 = pkmin(a2, v.z + cst); a3 = pkmin(a3, v.w + cst);          \
                ++jhi;                                                         \
            }                                                                  \
        }                                                                      \
    }

// ---------------------------------------------------------------------------
// Kernel A: block = (b,c,d), 512 threads.
//  (0) block 0 zeroes B's last-block counter (stream order covers visibility).
//  (p) threads 0-255 PREFETCH their 4 pred float4s (latency hides under W/H).
//  (1) W-pass: 8 waves x 8 rows, ballot nearest-set-bit -> u16 LDS.
//  (2) H-pass: packed-u16 early-exit min-plus -> dsqT[b][c][h][d][w].
//  (3) softmax from prefetched registers -> probH (packed fp16).
// ---------------------------------------------------------------------------
__global__ __launch_bounds__(512) void edt_wh_prob(const int* __restrict__ tgt,
                                                   const float* __restrict__ pred,
                                                   u16* __restrict__ dsqT,
                                                   u16* __restrict__ probH,
                                                   unsigned int* __restrict__ counter) {
    __shared__ u16 fs[HW];   // 8 KB W-pass result [h][w]
    const int t    = threadIdx.x;
    const int blk  = blockIdx.x;
    if (blk == 0 && t == 0) *counter = 0u;

    const int lane = t & 63;
    const int wv   = t >> 6;           // 8 waves
    const int b = blk >> 8;
    const int c = (blk >> 6) & 3;
    const int d = blk & 63;
    const size_t tb = (size_t)(b * 64 + d) * HW;   // tgt[b][d][:][:]

    // Prefetch softmax inputs early; loads stay in flight during W/H phases.
    float4 q0, q1, q2, q3;
    const int hh = c * 16 + (t >> 4);
    const int w0 = (t & 15) * 4;
    if (t < 256) {
        const size_t pidx = (size_t)b * CDHW + (size_t)d * HW + (size_t)hh * 64 + w0;
        q0 = *reinterpret_cast<const float4*>(&pred[pidx]);
        q1 = *reinterpret_cast<const float4*>(&pred[pidx + (size_t)DHW]);
        q2 = *reinterpret_cast<const float4*>(&pred[pidx + 2 * (size_t)DHW]);
        q3 = *reinterpret_cast<const float4*>(&pred[pidx + 3 * (size_t)DHW]);
    }

    // W-pass: 8 rows per wave, ballot nearest-set-bit.
    #pragma unroll
    for (int r = 0; r < 8; ++r) {
        const int h   = wv * 8 + r;
        const int cls = tgt[tb + h * 64 + lane];
        const unsigned long long mask = __ballot(cls == c);
        const unsigned long long mlo  = mask & (~0ull >> (63 - lane));
        const unsigned long long mhi  = mask & (~0ull << lane);
        int dd = 1000;
        if (mlo) dd = lane - (63 - __builtin_clzll(mlo));
        if (mhi) dd = min(dd, (int)__builtin_ctzll(mhi) - lane);
        fs[h * 64 + lane] = (dd >= 1000) ? (u16)SENT : (u16)(dd * dd);
    }
    __syncthreads();

    // H-pass: 1 output row x 8 w per thread, early-exit scan.
    const int i  = t >> 3;          // output row 0..63
    const int wg = (t & 7) * 8;     // 8 consecutive w
    MINPLUS_SCAN(fs)
    *reinterpret_cast<uint4*>(&dsqT[((size_t)(b * 4 + c) * 64 + i) * HW + d * 64 + wg])
        = make_uint4(a0, a1, a2, a3);

    // Softmax from prefetched registers -> packed fp16.
    if (t < 256) {
        float4 o0, o1, o2, o3;
        #define SMAX(X)                                                          \
        {   const float m = fmaxf(fmaxf(q0.X, q1.X), fmaxf(q2.X, q3.X));         \
            const float e0 = __expf(q0.X - m), e1 = __expf(q1.X - m),            \
                        e2 = __expf(q2.X - m), e3 = __expf(q3.X - m);            \
            const float zinv = 1.0f / (e0 + e1 + e2 + e3);                       \
            o0.X = e0 * zinv; o1.X = e1 * zinv;                                  \
            o2.X = e2 * zinv; o3.X = e3 * zinv; }
        SMAX(x) SMAX(y) SMAX(z) SMAX(w)
        #undef SMAX
        const size_t ob = (size_t)b * CDHW + (size_t)hh * HW + d * 64 + w0;
        #define PSTORE(cc, o)                                                    \
        {   const u32 lo = __builtin_bit_cast(u32, __floats2half2_rn(o.x, o.y)); \
            const u32 hi = __builtin_bit_cast(u32, __floats2half2_rn(o.z, o.w)); \
            *reinterpret_cast<uint2*>(&probH[ob + (size_t)cc * DHW]) =           \
                make_uint2(lo, hi); }
        PSTORE(0, o0) PSTORE(1, o1) PSTORE(2, o2) PSTORE(3, o3)
        #undef PSTORE
    }
}

// ---------------------------------------------------------------------------
// Kernel B: block = (b,c,h), 512 threads. Stage 8 KB u16 dsq slab + prefetch
// fp16 prob vector, early-exit min-plus along d, fused prob*sqrt reduce,
// partial store, then LIGHT-FENCE last-block final sum (t0-only release
// fence + 64-lane acquire fence; NOT the all-thread fence of R4/R5).
// ---------------------------------------------------------------------------
__global__ __launch_bounds__(512) void edt_d_reduce(const u16* __restrict__ dsqT,
                                                    const u16* __restrict__ probH,
                                                    float* __restrict__ partial,
                                                    unsigned int* __restrict__ counter,
                                                    float* __restrict__ out) {
    __shared__ u16   sdq[HW];   // 8 KB slab [d][w]
    __shared__ float wsum[8];
    __shared__ int   lastflag;
    const int t   = threadIdx.x;
    const int blk = blockIdx.x;
    const size_t base = (size_t)blk * HW;   // u16 units for both dsqT and probH

    const int i  = t >> 3;          // output d-row 0..63
    const int wg = (t & 7) * 8;

    // Issue both global loads back-to-back (one exposed latency).
    const uint4 s0 = reinterpret_cast<const uint4*>(&dsqT[base])[t];
    const uint4 pv = *reinterpret_cast<const uint4*>(&probH[base + i * 64 + wg]);
    reinterpret_cast<uint4*>(sdq)[t] = s0;
    __syncthreads();

    MINPLUS_SCAN(sdq)

    // Fused reduce: fp16 prob * sqrt(dsq), 8 points per thread.
    const float2 f0 = h2f(pv.x), f1 = h2f(pv.y), f2 = h2f(pv.z), f3 = h2f(pv.w);
    float vsum =
        f0.x * sqrtf((float)(a0 & 0xFFFFu)) + f0.y * sqrtf((float)(a0 >> 16)) +
        f1.x * sqrtf((float)(a1 & 0xFFFFu)) + f1.y * sqrtf((float)(a1 >> 16)) +
        f2.x * sqrtf((float)(a2 & 0xFFFFu)) + f2.y * sqrtf((float)(a2 >> 16)) +
        f3.x * sqrtf((float)(a3 & 0xFFFFu)) + f3.y * sqrtf((float)(a3 >> 16));

    const int lane = t & 63;
    #pragma unroll
    for (int off = 32; off > 0; off >>= 1) vsum += __shfl_down(vsum, off, 64);
    if (lane == 0) wsum[t >> 6] = vsum;
    __syncthreads();

    // Light-fence last-block tail.
    if (t == 0) {
        float s = 0.f;
        #pragma unroll
        for (int k = 0; k < 8; ++k) s += wsum[k];
        partial[blk] = s;
        __threadfence();                            // release (1 thread/block)
        lastflag = (atomicAdd(counter, 1u) == (unsigned)(NBLK - 1));
    }
    __syncthreads();
    if (lastflag && t < 64) {
        __threadfence();                            // acquire (64 lanes, once)
        double s = 0.0;
        #pragma unroll
        for (int k = 0; k < 8; ++k) s += (double)partial[t + k * 64];
        #pragma unroll
        for (int off = 32; off > 0; off >>= 1) s += __shfl_down(s, off, 64);
        if (t == 0) out[0] = (float)(s / (double)NTOT);
    }
}

// ---------------------------------------------------------------------------
extern "C" void kernel_launch(void* const* d_in, const int* in_sizes, int n_in,
                              void* d_out, int out_size, void* d_ws, size_t ws_size,
                              hipStream_t stream) {
    const float* pred = (const float*)d_in[0];
    const int*   tgt  = (const int*)d_in[1];
    float* out     = (float*)d_out;
    u16*   dsqT    = (u16*)d_ws;                          // NTOT u16 (4 MB)
    u16*   probH   = dsqT + NTOT;                         // NTOT u16 (4 MB)
    float* partial = (float*)(probH + NTOT);              // NBLK floats
    unsigned int* counter = (unsigned int*)(partial + NBLK);

    hipLaunchKernelGGL(edt_wh_prob,  dim3(NBLK), dim3(512), 0, stream,
                       tgt, pred, dsqT, probH, counter);
    hipLaunchKernelGGL(edt_d_reduce, dim3(NBLK), dim3(512), 0, stream,
                       dsqT, probH, partial, counter, out);
}

// Round 14
// 19.044 us; speedup vs baseline: 1.3876x; 1.3876x over previous
//
#include <hip/hip_runtime.h>
#include <hip/hip_fp16.h>
#include <math.h>

typedef unsigned short u16;
typedef unsigned int   u32;
typedef u16 us2 __attribute__((ext_vector_type(2)));

constexpr int BB = 2, CC = 4, DD = 64, HH = 64, WW = 64;
constexpr int HW   = HH * WW;      // 4096
constexpr int DHW  = DD * HW;      // 262144
constexpr int CDHW = CC * DHW;     // 1048576
constexpr int NTOT = BB * CDHW;    // 2097152
constexpr int NBLK = 512;
constexpr u32 SENT = 50000;        // u16 "infinity": 50000+2*3969 < 65536 (SWAR-safe)

__device__ __forceinline__ u32 pkmin(u32 a, u32 b) {
    us2 r = __builtin_elementwise_min(__builtin_bit_cast(us2, a),
                                      __builtin_bit_cast(us2, b));
    return __builtin_bit_cast(u32, r);
}
__device__ __forceinline__ u32 pkmax(u32 a, u32 b) {
    us2 r = __builtin_elementwise_max(__builtin_bit_cast(us2, a),
                                      __builtin_bit_cast(us2, b));
    return __builtin_bit_cast(u32, r);
}
__device__ __forceinline__ float2 h2f(u32 w) {
    return __half22float2(__builtin_bit_cast(__half2, w));
}

// Min-plus over rows of a [64][64] u16 LDS slab with outward early-exit
// (R12-proven, lossless: only provably-non-improving j rows are skipped).
#define MINPLUS_SCAN(SRC)                                                      \
    u32 a0 = 0xFFFFFFFFu, a1 = 0xFFFFFFFFu, a2 = 0xFFFFFFFFu, a3 = 0xFFFFFFFFu;\
    {                                                                          \
        const int I = (t >> 6) * 8;                                            \
        _Pragma("unroll")                                                      \
        for (int k = 0; k < 8; ++k) {                                          \
            const int jj = I + k;                                              \
            const uint4 v = *reinterpret_cast<const uint4*>(&SRC[jj * 64 + wg]);\
            const int  df = i - jj;                                            \
            const u32  cst = (u32)(df * df) * 0x00010001u;                     \
            a0 = pkmin(a0, v.x + cst); a1 = pkmin(a1, v.y + cst);              \
            a2 = pkmin(a2, v.z + cst); a3 = pkmin(a3, v.w + cst);              \
        }                                                                      \
        int jlo = I - 1, jhi = I + 8;                                          \
        while (jlo >= 0 || jhi < 64) {                                         \
            const u32 pk  = pkmax(pkmax(a0, a1), pkmax(a2, a3));               \
            const u32 lo16 = pk & 0xFFFFu, hi16 = pk >> 16;                    \
            const u32 mm  = lo16 > hi16 ? lo16 : hi16;                         \
            const int dlo = (jlo >= 0) ? (i - jlo) : 1000;                     \
            const int dhi = (jhi < 64) ? (jhi - i) : 1000;                     \
            const int dm  = dlo < dhi ? dlo : dhi;                             \
            if (__all((u32)(dm * dm) >= mm)) break;                            \
            if (jlo >= 0) {                                                    \
                const uint4 v = *reinterpret_cast<const uint4*>(&SRC[jlo * 64 + wg]);\
                const int  df = i - jlo;                                       \
                const u32  cst = (u32)(df * df) * 0x00010001u;                 \
                a0 = pkmin(a0, v.x + cst); a1 = pkmin(a1, v.y + cst);          \
                a2 = pkmin(a2, v.z + cst); a3 = pkmin(a3, v.w + cst);          \
                --jlo;                                                         \
            }                                                                  \
            if (jhi < 64) {                                                    \
                const uint4 v = *reinterpret_cast<const uint4*>(&SRC[jhi * 64 + wg]);\
                const int  df = jhi - i;                                       \
                const u32  cst = (u32)(df * df) * 0x00010001u;                 \
                a0 = pkmin(a0, v.x + cst); a1 = pkmin(a1, v.y + cst);          \
                a2 = pkmin(a2, v.z + cst); a3 = pkmin(a3, v.w + cst);          \
                ++jhi;                                                         \
            }                                                                  \
        }                                                                      \
    }

// ---------------------------------------------------------------------------
// Kernel A: block = (b,c,d), 512 threads (R12 structure + pred prefetch).
//  (p) threads 0-255 prefetch their 4 pred float4s (hide under W/H phases).
//  (1) W-pass: 8 waves x 8 rows, ballot nearest-set-bit -> u16 LDS.
//  (2) H-pass: packed-u16 early-exit min-plus -> dsqT[b][c][h][d][w].
//  (3) softmax from prefetched registers -> probH (packed fp16).
// ---------------------------------------------------------------------------
__global__ __launch_bounds__(512) void edt_wh_prob(const int* __restrict__ tgt,
                                                   const float* __restrict__ pred,
                                                   u16* __restrict__ dsqT,
                                                   u16* __restrict__ probH) {
    __shared__ u16 fs[HW];   // 8 KB W-pass result [h][w]
    const int t    = threadIdx.x;
    const int blk  = blockIdx.x;
    const int lane = t & 63;
    const int wv   = t >> 6;           // 8 waves
    const int b = blk >> 8;
    const int c = (blk >> 6) & 3;
    const int d = blk & 63;
    const size_t tb = (size_t)(b * 64 + d) * HW;   // tgt[b][d][:][:]

    // Prefetch softmax inputs; loads stay in flight during W/H phases.
    float4 q0, q1, q2, q3;
    const int hh = c * 16 + (t >> 4);
    const int w0 = (t & 15) * 4;
    if (t < 256) {
        const size_t pidx = (size_t)b * CDHW + (size_t)d * HW + (size_t)hh * 64 + w0;
        q0 = *reinterpret_cast<const float4*>(&pred[pidx]);
        q1 = *reinterpret_cast<const float4*>(&pred[pidx + (size_t)DHW]);
        q2 = *reinterpret_cast<const float4*>(&pred[pidx + 2 * (size_t)DHW]);
        q3 = *reinterpret_cast<const float4*>(&pred[pidx + 3 * (size_t)DHW]);
    }

    // W-pass: 8 rows per wave, ballot nearest-set-bit.
    #pragma unroll
    for (int r = 0; r < 8; ++r) {
        const int h   = wv * 8 + r;
        const int cls = tgt[tb + h * 64 + lane];
        const unsigned long long mask = __ballot(cls == c);
        const unsigned long long mlo  = mask & (~0ull >> (63 - lane));
        const unsigned long long mhi  = mask & (~0ull << lane);
        int dd = 1000;
        if (mlo) dd = lane - (63 - __builtin_clzll(mlo));
        if (mhi) dd = min(dd, (int)__builtin_ctzll(mhi) - lane);
        fs[h * 64 + lane] = (dd >= 1000) ? (u16)SENT : (u16)(dd * dd);
    }
    __syncthreads();

    // H-pass: 1 output row x 8 w per thread, early-exit scan.
    const int i  = t >> 3;          // output row 0..63
    const int wg = (t & 7) * 8;     // 8 consecutive w
    MINPLUS_SCAN(fs)
    *reinterpret_cast<uint4*>(&dsqT[((size_t)(b * 4 + c) * 64 + i) * HW + d * 64 + wg])
        = make_uint4(a0, a1, a2, a3);

    // Softmax from prefetched registers -> packed fp16.
    if (t < 256) {
        float4 o0, o1, o2, o3;
        #define SMAX(X)                                                          \
        {   const float m = fmaxf(fmaxf(q0.X, q1.X), fmaxf(q2.X, q3.X));         \
            const float e0 = __expf(q0.X - m), e1 = __expf(q1.X - m),            \
                        e2 = __expf(q2.X - m), e3 = __expf(q3.X - m);            \
            const float zinv = 1.0f / (e0 + e1 + e2 + e3);                       \
            o0.X = e0 * zinv; o1.X = e1 * zinv;                                  \
            o2.X = e2 * zinv; o3.X = e3 * zinv; }
        SMAX(x) SMAX(y) SMAX(z) SMAX(w)
        #undef SMAX
        const size_t ob = (size_t)b * CDHW + (size_t)hh * HW + d * 64 + w0;
        #define PSTORE(cc, o)                                                    \
        {   const u32 lo = __builtin_bit_cast(u32, __floats2half2_rn(o.x, o.y)); \
            const u32 hi = __builtin_bit_cast(u32, __floats2half2_rn(o.z, o.w)); \
            *reinterpret_cast<uint2*>(&probH[ob + (size_t)cc * DHW]) =           \
                make_uint2(lo, hi); }
        PSTORE(0, o0) PSTORE(1, o1) PSTORE(2, o2) PSTORE(3, o3)
        #undef PSTORE
    }
}

// ---------------------------------------------------------------------------
// Kernel B: block = (b,c,h), 512 threads (exact R12: no fences, no atomics).
// Stage 8 KB u16 dsq slab + prefetch fp16 prob vector, early-exit min-plus
// along d, fused prob*sqrt reduce, plain partial store.
// ---------------------------------------------------------------------------
__global__ __launch_bounds__(512) void edt_d_reduce(const u16* __restrict__ dsqT,
                                                    const u16* __restrict__ probH,
                                                    float* __restrict__ partial) {
    __shared__ u16   sdq[HW];   // 8 KB slab [d][w]
    __shared__ float wsum[8];
    const int t   = threadIdx.x;
    const int blk = blockIdx.x;
    const size_t base = (size_t)blk * HW;   // u16 units for both dsqT and probH

    const int i  = t >> 3;          // output d-row 0..63
    const int wg = (t & 7) * 8;

    // Issue both global loads back-to-back (one exposed latency).
    const uint4 s0 = reinterpret_cast<const uint4*>(&dsqT[base])[t];
    const uint4 pv = *reinterpret_cast<const uint4*>(&probH[base + i * 64 + wg]);
    reinterpret_cast<uint4*>(sdq)[t] = s0;
    __syncthreads();

    MINPLUS_SCAN(sdq)

    // Fused reduce: fp16 prob * sqrt(dsq), 8 points per thread.
    const float2 f0 = h2f(pv.x), f1 = h2f(pv.y), f2 = h2f(pv.z), f3 = h2f(pv.w);
    float vsum =
        f0.x * sqrtf((float)(a0 & 0xFFFFu)) + f0.y * sqrtf((float)(a0 >> 16)) +
        f1.x * sqrtf((float)(a1 & 0xFFFFu)) + f1.y * sqrtf((float)(a1 >> 16)) +
        f2.x * sqrtf((float)(a2 & 0xFFFFu)) + f2.y * sqrtf((float)(a2 >> 16)) +
        f3.x * sqrtf((float)(a3 & 0xFFFFu)) + f3.y * sqrtf((float)(a3 >> 16));

    const int lane = t & 63;
    #pragma unroll
    for (int off = 32; off > 0; off >>= 1) vsum += __shfl_down(vsum, off, 64);
    if (lane == 0) wsum[t >> 6] = vsum;
    __syncthreads();
    if (t == 0) {
        float s = 0.f;
        #pragma unroll
        for (int k = 0; k < 8; ++k) s += wsum[k];
        partial[blk] = s;
    }
}

// ---------------------------------------------------------------------------
// Kernel C: one-wave deterministic final sum (fixed lane-strided order).
// ---------------------------------------------------------------------------
__global__ __launch_bounds__(64) void bl_final(const float* __restrict__ partial,
                                               float* __restrict__ out) {
    const int t = threadIdx.x;
    double s = 0.0;
    #pragma unroll
    for (int k = 0; k < 8; ++k) s += (double)partial[t + k * 64];
    #pragma unroll
    for (int off = 32; off > 0; off >>= 1) s += __shfl_down(s, off, 64);
    if (t == 0) out[0] = (float)(s / (double)NTOT);
}

// ---------------------------------------------------------------------------
extern "C" void kernel_launch(void* const* d_in, const int* in_sizes, int n_in,
                              void* d_out, int out_size, void* d_ws, size_t ws_size,
                              hipStream_t stream) {
    const float* pred = (const float*)d_in[0];
    const int*   tgt  = (const int*)d_in[1];
    float* out     = (float*)d_out;
    u16*   dsqT    = (u16*)d_ws;                          // NTOT u16 (4 MB)
    u16*   probH   = dsqT + NTOT;                         // NTOT u16 (4 MB)
    float* partial = (float*)(probH + NTOT);              // NBLK floats

    hipLaunchKernelGGL(edt_wh_prob,  dim3(NBLK), dim3(512), 0, stream,
                       tgt, pred, dsqT, probH);
    hipLaunchKernelGGL(edt_d_reduce, dim3(NBLK), dim3(512), 0, stream,
                       dsqT, probH, partial);
    hipLaunchKernelGGL(bl_final,     dim3(1),    dim3(64),  0, stream,
                       partial, out);
}